// Round 6
// baseline (12056.665 us; speedup 1.0000x reference)
//
#include <hip/hip_runtime.h>
#include <hip/hip_bf16.h>

// Problem constants: B=32, D=128, T=2250, Q=32, K=1024
#define B_ 32
#define D_ 128
#define T_ 2250
#define Q_ 32
#define K_ 1024
#define N_ (B_ * T_)      // 72000
#define NPAD 72064        // 563 * 128
#define TAU 0.0625f

typedef short bf16x8 __attribute__((ext_vector_type(8)));
typedef float f32x4 __attribute__((ext_vector_type(4)));

__device__ __forceinline__ void split_bf16(float x, unsigned short& hb, unsigned short& lb) {
    __hip_bfloat16 h = __float2bfloat16(x);
    float hf = __bfloat162float(h);
    __hip_bfloat16 l = __float2bfloat16(x - hf);
    hb = *(unsigned short*)&h;
    lb = *(unsigned short*)&l;
}

// ---------------------------------------------------------------------------
// Transpose embeddings [B, D, T] -> R64 [N,128] fp64 + Rhi/Rlo [NPAD,128] bf16
// ---------------------------------------------------------------------------
__global__ void transpose_kernel(const float* __restrict__ emb,
                                 double* __restrict__ R64,
                                 unsigned short* __restrict__ Rhi,
                                 unsigned short* __restrict__ Rlo)
{
    __shared__ float tile[32][33];
    const int b  = blockIdx.z;
    const int t0 = blockIdx.x * 32;
    const int d0 = blockIdx.y * 32;

    for (int i = threadIdx.y; i < 32; i += 8) {
        int t = t0 + threadIdx.x;
        int d = d0 + i;
        tile[i][threadIdx.x] = (t < T_) ? emb[((size_t)b * D_ + d) * T_ + t] : 0.0f;
    }
    __syncthreads();
    for (int i = threadIdx.y; i < 32; i += 8) {
        int t = t0 + i;
        if (t < T_) {
            float v = tile[threadIdx.x][i];
            size_t o = ((size_t)b * T_ + t) * D_ + d0 + threadIdx.x;
            R64[o] = (double)v;
            unsigned short hb, lb;
            split_bf16(v, hb, lb);
            Rhi[o] = hb;
            Rlo[o] = lb;
        }
    }
}

// ---------------------------------------------------------------------------
// Codebook hi/lo split (once): [Q*K*D] fp32 -> bf16 hi + bf16 lo
// ---------------------------------------------------------------------------
__global__ void split_cb_kernel(const float* __restrict__ cbs,
                                unsigned short* __restrict__ Ehi,
                                unsigned short* __restrict__ Elo)
{
    int i = blockIdx.x * 256 + threadIdx.x;   // Q*K*D threads exactly
    float x = cbs[i];
    unsigned short hb, lb;
    split_bf16(x, hb, lb);
    Ehi[i] = hb;
    Elo[i] = lb;
}

// ---------------------------------------------------------------------------
// Per-code squared norms: fp32 (fast pass) and fp64 (rescore). One wave/code.
// ---------------------------------------------------------------------------
__global__ __launch_bounds__(64) void norms_kernel(const float* __restrict__ codebooks,
                                                   float* __restrict__ normF,
                                                   double* __restrict__ normD)
{
    const int code = blockIdx.x;            // 0 .. Q*K-1
    const float* e = codebooks + (size_t)code * D_;
    const int lane = threadIdx.x;
    float f0 = e[lane];
    float f1 = e[lane + 64];
    double acc = (double)f0 * (double)f0 + (double)f1 * (double)f1;
    #pragma unroll
    for (int off = 32; off > 0; off >>= 1) acc += __shfl_down(acc, off);
    if (lane == 0) {
        normD[code] = acc;
        normF[code] = (float)acc;
    }
}

// ---------------------------------------------------------------------------
// MFMA fast pass, barrier-free K-loop.
// Block = 128 points x ALL 1024 codes; 256 threads = 4 waves in 2x2.
// A (hi+lo, 64 KB, XOR-swizzled) resident in LDS; B frags register-double-
// buffered straight from global (L2-hot 1 MB layer slice), prefetch crosses
// stripe boundaries. Occupancy is LDS-capped at 2 blocks/CU = 2 waves/EU,
// so force the 256-VGPR budget (amdgpu_waves_per_eu(2,2)) to kill spills.
// ---------------------------------------------------------------------------
__global__ __launch_bounds__(256)
__attribute__((amdgpu_waves_per_eu(2, 2)))
void layer_fast(
    const unsigned short* __restrict__ Rhi,   // [NPAD,128]
    const unsigned short* __restrict__ Rlo,
    const unsigned short* __restrict__ Ehi,   // [K,128] (layer slice)
    const unsigned short* __restrict__ Elo,
    const float* __restrict__ normF,          // [K] (layer slice)
    int* __restrict__ outIdx,
    int* __restrict__ flagList,
    int* __restrict__ flagCount)
{
    __shared__ __align__(16) char lds[65536];  // A-hi [0,32K), A-lo [32K,64K)

    const int tid  = threadIdx.x;
    const int lane = tid & 63;
    const int w    = tid >> 6;
    const int wr   = w >> 1;            // wave point-row (0..1)
    const int wc   = w & 1;             // wave code-col (0..1)
    const int l15  = lane & 15;
    const int quad = lane >> 4;
    const int mBase = blockIdx.x * 128;

    // ---- Stage A hi+lo into LDS, XOR-swizzled granules (prologue, once) ----
    {
        const char* gh = (const char*)Rhi + (size_t)mBase * 256;
        const char* gl = (const char*)Rlo + (size_t)mBase * 256;
        #pragma unroll
        for (int i = 0; i < 8; ++i) {
            int slot = i * 256 + tid;              // 0..2047 (16-B granules)
            int row = slot >> 4, g = slot & 15;
            int lofs = row * 256 + ((g ^ (row & 15)) << 4);
            *(float4*)(lds + lofs)         = *(const float4*)(gh + slot * 16);
            *(float4*)(lds + 32768 + lofs) = *(const float4*)(gl + slot * 16);
        }
    }
    __syncthreads();

    // A fragment addressing: row = wr*64 + i*16 + l15 (row & 15 == l15)
    const int aRowByte = (wr * 64 + l15) * 256;
    int gofs[4];
    #pragma unroll
    for (int c = 0; c < 4; ++c) gofs[c] = (((c * 4 + quad) ^ l15) << 4);

    // B global lane base: code row = stripe*128 + wc*64 + j*16 + l15
    const size_t bLane = ((size_t)(wc * 64 + l15)) * 256 + (size_t)quad * 16;
    const char* BhBase = (const char*)Ehi + bLane;
    const char* BlBase = (const char*)Elo + bLane;

    // per-lane running top-2 for its 16 points (s = i*4 + r)
    float tb1[16], tb2[16]; int tk1[16];
    #pragma unroll
    for (int s = 0; s < 16; ++s) { tb1[s] = -3.4e38f; tb2[s] = -3.4e38f; tk1[s] = 0; }

    // prefetch (st=0, c=0)
    bf16x8 bh[4], bl[4];
    #pragma unroll
    for (int j = 0; j < 4; ++j) {
        bh[j] = *(const bf16x8*)(BhBase + j * 4096);
        bl[j] = *(const bf16x8*)(BlBase + j * 4096);
    }

    #pragma unroll 1
    for (int st = 0; st < 8; ++st) {
        f32x4 acc[4][4];
        #pragma unroll
        for (int i = 0; i < 4; ++i)
            #pragma unroll
            for (int j = 0; j < 4; ++j) acc[i][j] = (f32x4){0.f, 0.f, 0.f, 0.f};

        #pragma unroll
        for (int c = 0; c < 4; ++c) {
            // prefetch next c-group; at c==3 prefetch next stripe's c=0
            bf16x8 nbh[4], nbl[4];
            const bool haveNext = (c < 3) || (st < 7);
            if (haveNext) {
                size_t noff = (c < 3) ? ((size_t)st * 32768 + (size_t)(c + 1) * 64)
                                      : ((size_t)(st + 1) * 32768);
                #pragma unroll
                for (int j = 0; j < 4; ++j) {
                    nbh[j] = *(const bf16x8*)(BhBase + noff + j * 4096);
                    nbl[j] = *(const bf16x8*)(BlBase + noff + j * 4096);
                }
            }
            bf16x8 ah[4];
            #pragma unroll
            for (int i = 0; i < 4; ++i)
                ah[i] = *(const bf16x8*)(lds + aRowByte + i * 4096 + gofs[c]);
            #pragma unroll
            for (int i = 0; i < 4; ++i)
                #pragma unroll
                for (int j = 0; j < 4; ++j)
                    acc[i][j] = __builtin_amdgcn_mfma_f32_16x16x32_bf16(ah[i], bh[j], acc[i][j], 0, 0, 0);
            #pragma unroll
            for (int i = 0; i < 4; ++i)
                #pragma unroll
                for (int j = 0; j < 4; ++j)
                    acc[i][j] = __builtin_amdgcn_mfma_f32_16x16x32_bf16(ah[i], bl[j], acc[i][j], 0, 0, 0);
            bf16x8 al[4];
            #pragma unroll
            for (int i = 0; i < 4; ++i)
                al[i] = *(const bf16x8*)(lds + 32768 + aRowByte + i * 4096 + gofs[c]);
            #pragma unroll
            for (int i = 0; i < 4; ++i)
                #pragma unroll
                for (int j = 0; j < 4; ++j)
                    acc[i][j] = __builtin_amdgcn_mfma_f32_16x16x32_bf16(al[i], bh[j], acc[i][j], 0, 0, 0);
            if (haveNext) {
                #pragma unroll
                for (int j = 0; j < 4; ++j) { bh[j] = nbh[j]; bl[j] = nbl[j]; }
            }
        }

        // stripe epilogue: scores + running top-2 (j ascending = code ascending)
        float nf[4];
        #pragma unroll
        for (int j = 0; j < 4; ++j) nf[j] = normF[st * 128 + wc * 64 + j * 16 + l15];

        #pragma unroll
        for (int j = 0; j < 4; ++j) {
            const int code = st * 128 + wc * 64 + j * 16 + l15;
            #pragma unroll
            for (int i = 0; i < 4; ++i)
                #pragma unroll
                for (int r = 0; r < 4; ++r) {
                    float v = fmaf(2.0f, acc[i][j][r], -nf[j]);
                    const int s = i * 4 + r;
                    if (v > tb1[s])      { tb2[s] = tb1[s]; tb1[s] = v; tk1[s] = code; }
                    else if (v > tb2[s]) { tb2[s] = v; }
                }
        }
    }

    // ---- cross-l15 merge (butterfly over low 4 lane bits) ----
    #pragma unroll
    for (int m = 1; m < 16; m <<= 1) {
        #pragma unroll
        for (int s = 0; s < 16; ++s) {
            float ob1 = __shfl_xor(tb1[s], m);
            float ob2 = __shfl_xor(tb2[s], m);
            int   ok1 = __shfl_xor(tk1[s], m);
            if (ob1 > tb1[s] || (ob1 == tb1[s] && ok1 < tk1[s])) {
                tb2[s] = fmaxf(tb1[s], ob2);
                tb1[s] = ob1;
                tk1[s] = ok1;
            } else {
                tb2[s] = fmaxf(tb2[s], ob1);
            }
        }
    }

    // ---- cross-wave (wc) merge via small LDS buffer; write results ----
    __syncthreads();                     // done with A region
    float* mb1 = (float*)lds;            // [2][128]
    float* mb2 = (float*)(lds + 1024);
    int*   mk1 = (int*)(lds + 2048);
    if (l15 == 0) {
        #pragma unroll
        for (int i = 0; i < 4; ++i)
            #pragma unroll
            for (int r = 0; r < 4; ++r) {
                int p = wr * 64 + i * 16 + quad * 4 + r;
                mb1[wc * 128 + p] = tb1[i * 4 + r];
                mb2[wc * 128 + p] = tb2[i * 4 + r];
                mk1[wc * 128 + p] = tk1[i * 4 + r];
            }
    }
    __syncthreads();
    if (tid < 128) {
        float B1 = mb1[tid], B2 = mb2[tid];
        int   K1 = mk1[tid];
        float ob1 = mb1[128 + tid], ob2 = mb2[128 + tid];
        int   ok1 = mk1[128 + tid];
        if (ob1 > B1 || (ob1 == B1 && ok1 < K1)) { B2 = fmaxf(B1, ob2); B1 = ob1; K1 = ok1; }
        else                                     { B2 = fmaxf(B2, ob1); }
        const int n = mBase + tid;
        if (n < N_) {
            outIdx[n] = K1;
            if (B1 - B2 < TAU) {
                int pos = atomicAdd(flagCount, 1);
                flagList[pos] = n;
            }
        }
    }
}

// ---------------------------------------------------------------------------
// fp64 rescore of flagged points against the fp64 residual. One wave/point.
// ---------------------------------------------------------------------------
__global__ __launch_bounds__(64) void layer_rescore(
    const double* __restrict__ R64,
    const float* __restrict__ cb,
    const double* __restrict__ normD,
    const int* __restrict__ flagList,
    const int* __restrict__ flagCount,
    int* __restrict__ outIdx)
{
    const int cnt = *flagCount;
    const int lane = threadIdx.x;
    for (int i = blockIdx.x; i < cnt; i += gridDim.x) {
        const int n = flagList[i];
        const double* __restrict__ r = R64 + (size_t)n * D_;
        double best = -1.0e300;
        int bi = K_;
        for (int k = lane; k < K_; k += 64) {
            const float* __restrict__ c = cb + (size_t)k * D_;
            double a0 = 0.0, a1 = 0.0;
            #pragma unroll 8
            for (int j = 0; j < D_; j += 2) {
                a0 = fma(r[j],     (double)c[j],     a0);
                a1 = fma(r[j + 1], (double)c[j + 1], a1);
            }
            double s = 2.0 * (a0 + a1) - normD[k];
            if (s > best) { best = s; bi = k; }   // strict > : lowest k in lane wins
        }
        #pragma unroll
        for (int off = 32; off > 0; off >>= 1) {
            double ob = __shfl_down(best, off);
            int    oi = __shfl_down(bi, off);
            if (ob > best || (ob == best && oi < bi)) { best = ob; bi = oi; }
        }
        if (lane == 0) outIdx[n] = bi;
    }
}

// ---------------------------------------------------------------------------
// Residual update in fp64: R64 -= cb[idx]; refresh bf16 hi/lo shadows.
// ---------------------------------------------------------------------------
__global__ void layer_update(double* __restrict__ R64,
                             unsigned short* __restrict__ Rhi,
                             unsigned short* __restrict__ Rlo,
                             const float* __restrict__ cb,
                             const int* __restrict__ outIdx)
{
    const int tid = blockIdx.x * 256 + threadIdx.x;   // N*64 threads exactly
    const int n = tid >> 6;
    const int c = tid & 63;
    const int k = outIdx[n];
    double2 rv = ((double2*)R64)[tid];
    float2  cv = ((const float2*)cb)[(size_t)k * 64 + c];
    rv.x -= (double)cv.x;
    rv.y -= (double)cv.y;
    ((double2*)R64)[tid] = rv;
    unsigned short hx, lx, hy, ly;
    split_bf16((float)rv.x, hx, lx);
    split_bf16((float)rv.y, hy, ly);
    ((uint*)Rhi)[tid] = (uint)hx | ((uint)hy << 16);
    ((uint*)Rlo)[tid] = (uint)lx | ((uint)ly << 16);
}

// ---------------------------------------------------------------------------
extern "C" void kernel_launch(void* const* d_in, const int* in_sizes, int n_in,
                              void* d_out, int out_size, void* d_ws, size_t ws_size,
                              hipStream_t stream)
{
    const float* emb       = (const float*)d_in[0];   // [B, D, T] fp32
    const float* codebooks = (const float*)d_in[1];   // [Q, K, D] fp32
    int* outIdx = (int*)d_out;                        // [Q, B, T] int32

    char* ws = (char*)d_ws;
    double* R64  = (double*)ws;                        size_t off = (size_t)N_ * D_ * 8;
    double* normD = (double*)(ws + off);               off += (size_t)Q_ * K_ * 8;
    unsigned short* Rhi = (unsigned short*)(ws + off); off += (size_t)NPAD * D_ * 2;
    unsigned short* Rlo = (unsigned short*)(ws + off); off += (size_t)NPAD * D_ * 2;
    unsigned short* Ehi = (unsigned short*)(ws + off); off += (size_t)Q_ * K_ * D_ * 2;
    unsigned short* Elo = (unsigned short*)(ws + off); off += (size_t)Q_ * K_ * D_ * 2;
    float* normF    = (float*)(ws + off);              off += (size_t)Q_ * K_ * 4;
    int*   flagList = (int*)(ws + off);                off += (size_t)N_ * 4;
    int*   counters = (int*)(ws + off);                off += (size_t)Q_ * 4;

    hipMemsetAsync(counters, 0, Q_ * 4, stream);
    // zero the pad rows (72000..72063) of the bf16 shadows (guard-free staging)
    hipMemsetAsync((char*)Rhi + (size_t)N_ * 256, 0, (size_t)(NPAD - N_) * 256, stream);
    hipMemsetAsync((char*)Rlo + (size_t)N_ * 256, 0, (size_t)(NPAD - N_) * 256, stream);

    dim3 tb(32, 8, 1);
    dim3 tg((T_ + 31) / 32, D_ / 32, B_);
    transpose_kernel<<<tg, tb, 0, stream>>>(emb, R64, Rhi, Rlo);
    split_cb_kernel<<<(Q_ * K_ * D_) / 256, 256, 0, stream>>>(codebooks, Ehi, Elo);
    norms_kernel<<<Q_ * K_, 64, 0, stream>>>(codebooks, normF, normD);

    for (int q = 0; q < Q_; ++q) {
        const float* cb = codebooks + (size_t)q * K_ * D_;
        int* oq = outIdx + (size_t)q * N_;
        layer_fast<<<563, 256, 0, stream>>>(
            Rhi, Rlo, Ehi + (size_t)q * K_ * D_, Elo + (size_t)q * K_ * D_,
            normF + (size_t)q * K_, oq, flagList, counters + q);
        layer_rescore<<<2048, 64, 0, stream>>>(R64, cb, normD + (size_t)q * K_,
                                               flagList, counters + q, oq);
        if (q < Q_ - 1) {
            layer_update<<<(N_ * 64) / 256, 256, 0, stream>>>(R64, Rhi, Rlo, cb, oq);
        }
    }
}

// Round 7
// 8632.001 us; speedup vs baseline: 1.3967x; 1.3967x over previous
//
#include <hip/hip_runtime.h>
#include <hip/hip_bf16.h>

// Problem constants: B=32, D=128, T=2250, Q=32, K=1024
#define B_ 32
#define D_ 128
#define T_ 2250
#define Q_ 32
#define K_ 1024
#define N_ (B_ * T_)      // 72000
#define TAU 0.25f
#define COFF 640.0f       // score offset: v = 2 r.e + (COFF - ||e||^2), always in (1, 1024)

typedef short bf16x8 __attribute__((ext_vector_type(8)));
typedef float f32x4 __attribute__((ext_vector_type(4)));

__device__ __forceinline__ void split_bf16(float x, unsigned short& hb, unsigned short& lb) {
    __hip_bfloat16 h = __float2bfloat16(x);
    float hf = __bfloat162float(h);
    __hip_bfloat16 l = __float2bfloat16(x - hf);
    hb = *(unsigned short*)&h;
    lb = *(unsigned short*)&l;
}

// ---------------------------------------------------------------------------
// Transpose embeddings [B, D, T] -> R64 [N,128] fp64 (n = b*T + t)
// ---------------------------------------------------------------------------
__global__ void transpose_kernel(const float* __restrict__ emb,
                                 double* __restrict__ R64)
{
    __shared__ float tile[32][33];
    const int b  = blockIdx.z;
    const int t0 = blockIdx.x * 32;
    const int d0 = blockIdx.y * 32;

    for (int i = threadIdx.y; i < 32; i += 8) {
        int t = t0 + threadIdx.x;
        int d = d0 + i;
        tile[i][threadIdx.x] = (t < T_) ? emb[((size_t)b * D_ + d) * T_ + t] : 0.0f;
    }
    __syncthreads();
    for (int i = threadIdx.y; i < 32; i += 8) {
        int t = t0 + i;
        if (t < T_) {
            size_t o = ((size_t)b * T_ + t) * D_ + d0 + threadIdx.x;
            R64[o] = (double)tile[threadIdx.x][i];
        }
    }
}

// ---------------------------------------------------------------------------
// Codebook split with folded 2x: Eh2/El2 = bf16 split of (2*e)
// ---------------------------------------------------------------------------
__global__ void split_cb_kernel(const float* __restrict__ cbs,
                                unsigned short* __restrict__ Eh2,
                                unsigned short* __restrict__ El2)
{
    int i = blockIdx.x * 256 + threadIdx.x;   // Q*K*D threads exactly
    float x = 2.0f * cbs[i];
    unsigned short hb, lb;
    split_bf16(x, hb, lb);
    Eh2[i] = hb;
    El2[i] = lb;
}

// ---------------------------------------------------------------------------
// Per-code norms: cNorm = COFF - ||e||^2 (fp32, fast pass), normD = ||e||^2
// (fp64, rescore). One wave per code.
// ---------------------------------------------------------------------------
__global__ __launch_bounds__(64) void norms_kernel(const float* __restrict__ codebooks,
                                                   float* __restrict__ cNorm,
                                                   double* __restrict__ normD)
{
    const int code = blockIdx.x;            // 0 .. Q*K-1
    const float* e = codebooks + (size_t)code * D_;
    const int lane = threadIdx.x;
    float f0 = e[lane];
    float f1 = e[lane + 64];
    double acc = (double)f0 * (double)f0 + (double)f1 * (double)f1;
    #pragma unroll
    for (int off = 32; off > 0; off >>= 1) acc += __shfl_down(acc, off);
    if (lane == 0) {
        normD[code] = acc;
        cNorm[code] = COFF - (float)acc;
    }
}

// ---------------------------------------------------------------------------
// MFMA fast pass with FUSED fp64 residual update.
// Block = 128 points x ALL 1024 codes; 256 threads = 4 waves in 2x2.
// Prologue: R64 -= cbPrev[prevIdx] (fp64, written back), split to bf16 hi/lo
// straight into LDS (XOR-swizzled). K-loop: barrier-free; A frags from LDS,
// B frags single-buffered transient loads from the L2-hot layer slice.
// Top-2 kept as PACKED uints (score key | 1023-code) -> 32 regs.
// ---------------------------------------------------------------------------
__global__ __launch_bounds__(256) void layer_fast(
    double* __restrict__ R64,                 // [N,128] read/modify/write
    const int* __restrict__ prevIdx,          // [N] previous layer's indices (null for q==0)
    const float* __restrict__ cbPrev,         // [K,128] previous layer's fp32 codebook
    const unsigned short* __restrict__ Eh2,   // [K,128] this layer, split of 2e (hi)
    const unsigned short* __restrict__ El2,   // [K,128] (lo)
    const float* __restrict__ cNorm,          // [K] COFF - ||e||^2
    int* __restrict__ outIdx,
    int* __restrict__ flagList,
    int* __restrict__ flagCount)
{
    __shared__ __align__(16) char lds[65536];  // A-hi [0,32K), A-lo [32K,64K)

    const int tid  = threadIdx.x;
    const int lane = tid & 63;
    const int w    = tid >> 6;
    const int mBase = blockIdx.x * 128;

    // ---- Prologue: fused residual update + bf16 split directly into LDS ----
    {
        double2* R64v = (double2*)R64;
        const float2* cbv = (const float2*)cbPrev;
        const int d = lane * 2;                                  // dims d, d+1
        const int gsh = ((d >> 3) << 4) /*granule*16*/;
        #pragma unroll 4
        for (int k = 0; k < 32; ++k) {
            const int row = k * 4 + w;        // wave-uniform local row
            const int grow = mBase + row;
            double rx = 0.0, ry = 0.0;
            if (grow < N_) {
                double2 rv = R64v[(size_t)grow * 64 + lane];
                rx = rv.x; ry = rv.y;
                if (prevIdx) {
                    int code = prevIdx[grow];                    // broadcast
                    float2 ev = cbv[(size_t)code * 64 + lane];   // coalesced row
                    rx -= (double)ev.x;
                    ry -= (double)ev.y;
                    double2 nv; nv.x = rx; nv.y = ry;
                    R64v[(size_t)grow * 64 + lane] = nv;
                }
            }
            unsigned short hx, lx, hy, ly;
            split_bf16((float)rx, hx, lx);
            split_bf16((float)ry, hy, ly);
            const int lofs = row * 256 + (gsh ^ ((row & 15) << 4)) + (d & 7) * 2;
            *(unsigned int*)(lds + lofs)         = (unsigned int)hx | ((unsigned int)hy << 16);
            *(unsigned int*)(lds + 32768 + lofs) = (unsigned int)lx | ((unsigned int)ly << 16);
        }
    }
    __syncthreads();

    const int wr   = w >> 1;            // wave point-row (0..1)
    const int wc   = w & 1;             // wave code-col (0..1)
    const int l15  = lane & 15;
    const int quad = lane >> 4;

    // A fragment addressing (XOR-swizzled granules; row & 15 == l15)
    const int aRowByte = (wr * 64 + l15) * 256;
    int gofs[4];
    #pragma unroll
    for (int c = 0; c < 4; ++c) gofs[c] = (((c * 4 + quad) ^ l15) << 4);

    // B global lane base: code row = st*128 + wc*64 + j*16 + l15
    const size_t bLane = ((size_t)(wc * 64 + l15)) * 256 + (size_t)quad * 16;
    const char* BhB = (const char*)Eh2 + bLane;
    const char* BlB = (const char*)El2 + bLane;

    // packed running top-2 for this lane's 16 points (s = i*4 + r)
    unsigned int b1[16], b2[16];
    #pragma unroll
    for (int s = 0; s < 16; ++s) { b1[s] = 0u; b2[s] = 0u; }

    #pragma unroll 1
    for (int st = 0; st < 8; ++st) {
        f32x4 acc[4][4];
        #pragma unroll
        for (int i = 0; i < 4; ++i)
            #pragma unroll
            for (int j = 0; j < 4; ++j) acc[i][j] = (f32x4){0.f, 0.f, 0.f, 0.f};

        #pragma unroll
        for (int c = 0; c < 4; ++c) {
            const size_t boff = (size_t)st * 32768 + (size_t)c * 64;
            bf16x8 bh[4], bl[4];
            #pragma unroll
            for (int j = 0; j < 4; ++j) {
                bh[j] = *(const bf16x8*)(BhB + boff + j * 4096);
                bl[j] = *(const bf16x8*)(BlB + boff + j * 4096);
            }
            bf16x8 ah[4];
            #pragma unroll
            for (int i = 0; i < 4; ++i)
                ah[i] = *(const bf16x8*)(lds + aRowByte + i * 4096 + gofs[c]);
            #pragma unroll
            for (int i = 0; i < 4; ++i)
                #pragma unroll
                for (int j = 0; j < 4; ++j)
                    acc[i][j] = __builtin_amdgcn_mfma_f32_16x16x32_bf16(ah[i], bh[j], acc[i][j], 0, 0, 0);
            #pragma unroll
            for (int i = 0; i < 4; ++i)
                #pragma unroll
                for (int j = 0; j < 4; ++j)
                    acc[i][j] = __builtin_amdgcn_mfma_f32_16x16x32_bf16(ah[i], bl[j], acc[i][j], 0, 0, 0);
            bf16x8 al[4];
            #pragma unroll
            for (int i = 0; i < 4; ++i)
                al[i] = *(const bf16x8*)(lds + 32768 + aRowByte + i * 4096 + gofs[c]);
            #pragma unroll
            for (int i = 0; i < 4; ++i)
                #pragma unroll
                for (int j = 0; j < 4; ++j)
                    acc[i][j] = __builtin_amdgcn_mfma_f32_16x16x32_bf16(al[i], bh[j], acc[i][j], 0, 0, 0);
        }

        // epilogue: pack scores, update packed top-2 (near-ties resolved by rescore)
        #pragma unroll
        for (int j = 0; j < 4; ++j) {
            const int code = st * 128 + wc * 64 + j * 16 + l15;
            const float cn = cNorm[code];
            const unsigned int invc = 1023u - (unsigned int)code;
            #pragma unroll
            for (int i = 0; i < 4; ++i)
                #pragma unroll
                for (int r = 0; r < 4; ++r) {
                    float v = fmaxf(acc[i][j][r] + cn, 1.0f);    // positive -> uint-ordered
                    unsigned int p = (__float_as_uint(v) & 0xFFFFFC00u) | invc;
                    const int s = i * 4 + r;
                    unsigned int t  = (b1[s] > p) ? b1[s] : p;
                    unsigned int mn = (b1[s] < p) ? b1[s] : p;
                    b2[s] = (b2[s] > mn) ? b2[s] : mn;
                    b1[s] = t;
                }
        }
    }

    // ---- cross-l15 merge (butterfly over low 4 lane bits), packed max/min ----
    #pragma unroll
    for (int m = 1; m < 16; m <<= 1) {
        #pragma unroll
        for (int s = 0; s < 16; ++s) {
            unsigned int o1 = (unsigned int)__shfl_xor((int)b1[s], m);
            unsigned int o2 = (unsigned int)__shfl_xor((int)b2[s], m);
            unsigned int n1 = (b1[s] > o1) ? b1[s] : o1;
            unsigned int mn = (b1[s] < o1) ? b1[s] : o1;
            unsigned int mx2 = (b2[s] > o2) ? b2[s] : o2;
            b2[s] = (mn > mx2) ? mn : mx2;
            b1[s] = n1;
        }
    }

    // ---- cross-wave (wc) merge via small LDS buffer; write results ----
    __syncthreads();                     // done with A region
    unsigned int* m1 = (unsigned int*)lds;            // [2][128]
    unsigned int* m2 = (unsigned int*)(lds + 1024);
    if (l15 == 0) {
        #pragma unroll
        for (int i = 0; i < 4; ++i)
            #pragma unroll
            for (int r = 0; r < 4; ++r) {
                int p = wr * 64 + i * 16 + quad * 4 + r;
                m1[wc * 128 + p] = b1[i * 4 + r];
                m2[wc * 128 + p] = b2[i * 4 + r];
            }
    }
    __syncthreads();
    if (tid < 128) {
        unsigned int a1 = m1[tid], a2 = m2[tid];
        unsigned int c1 = m1[128 + tid], c2 = m2[128 + tid];
        unsigned int f1 = (a1 > c1) ? a1 : c1;
        unsigned int mn = (a1 < c1) ? a1 : c1;
        unsigned int mx2 = (a2 > c2) ? a2 : c2;
        unsigned int f2 = (mn > mx2) ? mn : mx2;
        const int n = mBase + tid;
        if (n < N_) {
            outIdx[n] = 1023 - (int)(f1 & 0x3FFu);
            float g1 = __uint_as_float(f1 & 0xFFFFFC00u);
            float g2 = __uint_as_float(f2 & 0xFFFFFC00u);
            if (g1 - g2 < TAU) {
                int pos = atomicAdd(flagCount, 1);
                flagList[pos] = n;
            }
        }
    }
}

// ---------------------------------------------------------------------------
// fp64 rescore of flagged points against the fp64 residual. One wave/point.
// ---------------------------------------------------------------------------
__global__ __launch_bounds__(64) void layer_rescore(
    const double* __restrict__ R64,
    const float* __restrict__ cb,
    const double* __restrict__ normD,
    const int* __restrict__ flagList,
    const int* __restrict__ flagCount,
    int* __restrict__ outIdx)
{
    const int cnt = *flagCount;
    const int lane = threadIdx.x;
    for (int i = blockIdx.x; i < cnt; i += gridDim.x) {
        const int n = flagList[i];
        const double* __restrict__ r = R64 + (size_t)n * D_;
        double best = -1.0e300;
        int bi = K_;
        for (int k = lane; k < K_; k += 64) {
            const float* __restrict__ c = cb + (size_t)k * D_;
            double a0 = 0.0, a1 = 0.0;
            #pragma unroll 8
            for (int j = 0; j < D_; j += 2) {
                a0 = fma(r[j],     (double)c[j],     a0);
                a1 = fma(r[j + 1], (double)c[j + 1], a1);
            }
            double s = 2.0 * (a0 + a1) - normD[k];
            if (s > best) { best = s; bi = k; }   // strict > : lowest k in lane wins
        }
        #pragma unroll
        for (int off = 32; off > 0; off >>= 1) {
            double ob = __shfl_down(best, off);
            int    oi = __shfl_down(bi, off);
            if (ob > best || (ob == best && oi < bi)) { best = ob; bi = oi; }
        }
        if (lane == 0) outIdx[n] = bi;
    }
}

// ---------------------------------------------------------------------------
extern "C" void kernel_launch(void* const* d_in, const int* in_sizes, int n_in,
                              void* d_out, int out_size, void* d_ws, size_t ws_size,
                              hipStream_t stream)
{
    const float* emb       = (const float*)d_in[0];   // [B, D, T] fp32
    const float* codebooks = (const float*)d_in[1];   // [Q, K, D] fp32
    int* outIdx = (int*)d_out;                        // [Q, B, T] int32

    char* ws = (char*)d_ws;
    double* R64  = (double*)ws;                        size_t off = (size_t)N_ * D_ * 8;
    double* normD = (double*)(ws + off);               off += (size_t)Q_ * K_ * 8;
    unsigned short* Eh2 = (unsigned short*)(ws + off); off += (size_t)Q_ * K_ * D_ * 2;
    unsigned short* El2 = (unsigned short*)(ws + off); off += (size_t)Q_ * K_ * D_ * 2;
    float* cNorm    = (float*)(ws + off);              off += (size_t)Q_ * K_ * 4;
    int*   flagList = (int*)(ws + off);                off += (size_t)N_ * 4;
    int*   counters = (int*)(ws + off);                off += (size_t)Q_ * 4;

    hipMemsetAsync(counters, 0, Q_ * 4, stream);

    dim3 tb(32, 8, 1);
    dim3 tg((T_ + 31) / 32, D_ / 32, B_);
    transpose_kernel<<<tg, tb, 0, stream>>>(emb, R64);
    split_cb_kernel<<<(Q_ * K_ * D_) / 256, 256, 0, stream>>>(codebooks, Eh2, El2);
    norms_kernel<<<Q_ * K_, 64, 0, stream>>>(codebooks, cNorm, normD);

    for (int q = 0; q < Q_; ++q) {
        int* oq = outIdx + (size_t)q * N_;
        const int* prevIdx = (q > 0) ? (outIdx + (size_t)(q - 1) * N_) : nullptr;
        const float* cbPrev = codebooks + (size_t)(q > 0 ? q - 1 : 0) * K_ * D_;
        layer_fast<<<563, 256, 0, stream>>>(
            R64, prevIdx, cbPrev,
            Eh2 + (size_t)q * K_ * D_, El2 + (size_t)q * K_ * D_,
            cNorm + (size_t)q * K_, oq, flagList, counters + q);
        layer_rescore<<<2048, 64, 0, stream>>>(
            R64, codebooks + (size_t)q * K_ * D_, normD + (size_t)q * K_,
            flagList, counters + q, oq);
    }
}

// Round 8
// 8059.129 us; speedup vs baseline: 1.4960x; 1.0711x over previous
//
#include <hip/hip_runtime.h>
#include <hip/hip_bf16.h>

// Problem constants: B=32, D=128, T=2250, Q=32, K=1024
#define B_ 32
#define D_ 128
#define T_ 2250
#define Q_ 32
#define K_ 1024
#define N_ (B_ * T_)      // 72000 = 64 * 1125
#define TAU 0.25f
#define COFF 640.0f       // score offset: v = 2 r.e + (COFF - ||e||^2), positive for this data

typedef short bf16x8 __attribute__((ext_vector_type(8)));
typedef float f32x4 __attribute__((ext_vector_type(4)));

__device__ __forceinline__ void split_bf16(float x, unsigned short& hb, unsigned short& lb) {
    __hip_bfloat16 h = __float2bfloat16(x);
    float hf = __bfloat162float(h);
    __hip_bfloat16 l = __float2bfloat16(x - hf);
    hb = *(unsigned short*)&h;
    lb = *(unsigned short*)&l;
}

// ---------------------------------------------------------------------------
// Transpose embeddings [B, D, T] -> R64 [N,128] fp64 (n = b*T + t)
// ---------------------------------------------------------------------------
__global__ void transpose_kernel(const float* __restrict__ emb,
                                 double* __restrict__ R64)
{
    __shared__ float tile[32][33];
    const int b  = blockIdx.z;
    const int t0 = blockIdx.x * 32;
    const int d0 = blockIdx.y * 32;

    for (int i = threadIdx.y; i < 32; i += 8) {
        int t = t0 + threadIdx.x;
        int d = d0 + i;
        tile[i][threadIdx.x] = (t < T_) ? emb[((size_t)b * D_ + d) * T_ + t] : 0.0f;
    }
    __syncthreads();
    for (int i = threadIdx.y; i < 32; i += 8) {
        int t = t0 + i;
        if (t < T_) {
            size_t o = ((size_t)b * T_ + t) * D_ + d0 + threadIdx.x;
            R64[o] = (double)tile[threadIdx.x][i];
        }
    }
}

// ---------------------------------------------------------------------------
// Codebook split with folded 2x: Eh2/El2 = bf16 split of (2*e)
// ---------------------------------------------------------------------------
__global__ void split_cb_kernel(const float* __restrict__ cbs,
                                unsigned short* __restrict__ Eh2,
                                unsigned short* __restrict__ El2)
{
    int i = blockIdx.x * 256 + threadIdx.x;   // Q*K*D threads exactly
    float x = 2.0f * cbs[i];
    unsigned short hb, lb;
    split_bf16(x, hb, lb);
    Eh2[i] = hb;
    El2[i] = lb;
}

// ---------------------------------------------------------------------------
// Per-code norms: cNorm = COFF - ||e||^2 (fp32), normD = ||e||^2 (fp64)
// ---------------------------------------------------------------------------
__global__ __launch_bounds__(64) void norms_kernel(const float* __restrict__ codebooks,
                                                   float* __restrict__ cNorm,
                                                   double* __restrict__ normD)
{
    const int code = blockIdx.x;            // 0 .. Q*K-1
    const float* e = codebooks + (size_t)code * D_;
    const int lane = threadIdx.x;
    float f0 = e[lane];
    float f1 = e[lane + 64];
    double acc = (double)f0 * (double)f0 + (double)f1 * (double)f1;
    #pragma unroll
    for (int off = 32; off > 0; off >>= 1) acc += __shfl_down(acc, off);
    if (lane == 0) {
        normD[code] = acc;
        cNorm[code] = COFF - (float)acc;
    }
}

// ---------------------------------------------------------------------------
// MFMA fast pass with fused fp64 residual update.
// Block = 64 points x ALL 1024 codes; 256 threads = 4 waves.
// Stripes of 128 codes; wave w owns the 32-code column [w*32, w*32+32).
// LDS 32 KB (A-hi 16K + A-lo 16K, XOR-swizzled) -> high occupancy for
// latency hiding; acc = 32 regs (64pt x 32code wave tile), packed top-2.
// ---------------------------------------------------------------------------
__global__ __launch_bounds__(256) void layer_fast(
    double* __restrict__ R64,                 // [N,128] read/modify/write
    const int* __restrict__ prevIdx,          // [N] prev layer's indices (null for q==0)
    const float* __restrict__ cbPrev,         // [K,128] prev layer's fp32 codebook
    const unsigned short* __restrict__ Eh2,   // [K,128] split of 2e (hi)
    const unsigned short* __restrict__ El2,   // [K,128] (lo)
    const float* __restrict__ cNorm,          // [K] COFF - ||e||^2
    int* __restrict__ outIdx,
    int* __restrict__ flagList,
    int* __restrict__ flagCount)
{
    __shared__ __align__(16) char lds[32768];  // A-hi [0,16K), A-lo [16K,32K)

    const int tid  = threadIdx.x;
    const int lane = tid & 63;
    const int w    = tid >> 6;
    const int mBase = blockIdx.x * 64;        // grid 1125 -> exact, no guards

    // ---- Prologue: fused fp64 residual update + bf16 split into LDS ----
    {
        double2* R64v = (double2*)R64;
        const float2* cbv = (const float2*)cbPrev;
        const int d = lane * 2;                   // dims d, d+1
        const int gsh = ((d >> 3) << 4);          // granule*16
        #pragma unroll 4
        for (int k = 0; k < 16; ++k) {
            const int row = k * 4 + w;            // wave-uniform local row
            const int grow = mBase + row;
            double2 rv = R64v[(size_t)grow * 64 + lane];
            double rx = rv.x, ry = rv.y;
            if (prevIdx) {
                int code = prevIdx[grow];                    // wave-uniform
                float2 ev = cbv[(size_t)code * 64 + lane];   // coalesced row
                rx -= (double)ev.x;
                ry -= (double)ev.y;
                double2 nv; nv.x = rx; nv.y = ry;
                R64v[(size_t)grow * 64 + lane] = nv;
            }
            unsigned short hx, lx, hy, ly;
            split_bf16((float)rx, hx, lx);
            split_bf16((float)ry, hy, ly);
            const int lofs = row * 256 + (gsh ^ ((row & 15) << 4)) + (d & 7) * 2;
            *(unsigned int*)(lds + lofs)         = (unsigned int)hx | ((unsigned int)hy << 16);
            *(unsigned int*)(lds + 16384 + lofs) = (unsigned int)lx | ((unsigned int)ly << 16);
        }
    }
    __syncthreads();

    const int l15  = lane & 15;
    const int quad = lane >> 4;

    // A fragment addressing (XOR-swizzled granules; frag rows have row&15==l15)
    const int aRowByte = l15 * 256;               // + i*4096 for i-th 16-row group
    int gofs[4];
    #pragma unroll
    for (int c = 0; c < 4; ++c) gofs[c] = (((c * 4 + quad) ^ l15) << 4);

    // B global lane base: code row = st*128 + w*32 + j*16 + l15
    const size_t bLane = ((size_t)(w * 32 + l15)) * 256 + (size_t)quad * 16;
    const char* BhB = (const char*)Eh2 + bLane;
    const char* BlB = (const char*)El2 + bLane;

    // packed running top-2 for this lane's 16 points (s = i*4 + r)
    unsigned int b1[16], b2[16];
    #pragma unroll
    for (int s = 0; s < 16; ++s) { b1[s] = 0u; b2[s] = 0u; }

    #pragma unroll 1
    for (int st = 0; st < 8; ++st) {
        f32x4 acc[4][2];
        #pragma unroll
        for (int i = 0; i < 4; ++i)
            #pragma unroll
            for (int j = 0; j < 2; ++j) acc[i][j] = (f32x4){0.f, 0.f, 0.f, 0.f};

        #pragma unroll
        for (int c = 0; c < 4; ++c) {
            const size_t boff = (size_t)st * 32768 + (size_t)c * 64;
            bf16x8 bh[2], bl[2];
            #pragma unroll
            for (int j = 0; j < 2; ++j) {
                bh[j] = *(const bf16x8*)(BhB + boff + j * 4096);
                bl[j] = *(const bf16x8*)(BlB + boff + j * 4096);
            }
            bf16x8 ah[4];
            #pragma unroll
            for (int i = 0; i < 4; ++i)
                ah[i] = *(const bf16x8*)(lds + aRowByte + i * 4096 + gofs[c]);
            #pragma unroll
            for (int i = 0; i < 4; ++i)
                #pragma unroll
                for (int j = 0; j < 2; ++j)
                    acc[i][j] = __builtin_amdgcn_mfma_f32_16x16x32_bf16(ah[i], bh[j], acc[i][j], 0, 0, 0);
            #pragma unroll
            for (int i = 0; i < 4; ++i)
                #pragma unroll
                for (int j = 0; j < 2; ++j)
                    acc[i][j] = __builtin_amdgcn_mfma_f32_16x16x32_bf16(ah[i], bl[j], acc[i][j], 0, 0, 0);
            bf16x8 al[4];
            #pragma unroll
            for (int i = 0; i < 4; ++i)
                al[i] = *(const bf16x8*)(lds + 16384 + aRowByte + i * 4096 + gofs[c]);
            #pragma unroll
            for (int i = 0; i < 4; ++i)
                #pragma unroll
                for (int j = 0; j < 2; ++j)
                    acc[i][j] = __builtin_amdgcn_mfma_f32_16x16x32_bf16(al[i], bh[j], acc[i][j], 0, 0, 0);
        }

        // epilogue: pack scores, update packed top-2
        #pragma unroll
        for (int j = 0; j < 2; ++j) {
            const int code = st * 128 + w * 32 + j * 16 + l15;
            const float cn = cNorm[code];
            const unsigned int invc = 1023u - (unsigned int)code;
            #pragma unroll
            for (int i = 0; i < 4; ++i)
                #pragma unroll
                for (int r = 0; r < 4; ++r) {
                    float v = fmaxf(acc[i][j][r] + cn, 1.0f);    // positive -> uint-ordered
                    unsigned int p = (__float_as_uint(v) & 0xFFFFFC00u) | invc;
                    const int s = i * 4 + r;
                    unsigned int t  = (b1[s] > p) ? b1[s] : p;
                    unsigned int mn = (b1[s] < p) ? b1[s] : p;
                    b2[s] = (b2[s] > mn) ? b2[s] : mn;
                    b1[s] = t;
                }
        }
    }

    // ---- cross-l15 merge (butterfly over low 4 lane bits), packed ----
    #pragma unroll
    for (int m = 1; m < 16; m <<= 1) {
        #pragma unroll
        for (int s = 0; s < 16; ++s) {
            unsigned int o1 = (unsigned int)__shfl_xor((int)b1[s], m);
            unsigned int o2 = (unsigned int)__shfl_xor((int)b2[s], m);
            unsigned int n1 = (b1[s] > o1) ? b1[s] : o1;
            unsigned int mn = (b1[s] < o1) ? b1[s] : o1;
            unsigned int mx2 = (b2[s] > o2) ? b2[s] : o2;
            b2[s] = (mn > mx2) ? mn : mx2;
            b1[s] = n1;
        }
    }

    // ---- cross-wave merge (4 waves = 4 code bands) via LDS ----
    __syncthreads();                     // done with A region
    unsigned int* m1 = (unsigned int*)lds;            // [4][64]
    unsigned int* m2 = (unsigned int*)(lds + 1024);
    if (l15 == 0) {
        #pragma unroll
        for (int i = 0; i < 4; ++i)
            #pragma unroll
            for (int r = 0; r < 4; ++r) {
                int p = i * 16 + quad * 4 + r;
                m1[w * 64 + p] = b1[i * 4 + r];
                m2[w * 64 + p] = b2[i * 4 + r];
            }
    }
    __syncthreads();
    if (tid < 64) {
        unsigned int f1 = m1[tid], f2 = m2[tid];
        #pragma unroll
        for (int ww = 1; ww < 4; ++ww) {
            unsigned int c1 = m1[ww * 64 + tid], c2 = m2[ww * 64 + tid];
            unsigned int mn  = (f1 < c1) ? f1 : c1;
            f1               = (f1 > c1) ? f1 : c1;
            unsigned int mx2 = (f2 > c2) ? f2 : c2;
            f2 = (mn > mx2) ? mn : mx2;
        }
        const int n = mBase + tid;
        outIdx[n] = 1023 - (int)(f1 & 0x3FFu);
        float g1 = __uint_as_float(f1 & 0xFFFFFC00u);
        float g2 = __uint_as_float(f2 & 0xFFFFFC00u);
        if (g1 - g2 < TAU) {
            int pos = atomicAdd(flagCount, 1);
            flagList[pos] = n;
        }
    }
}

// ---------------------------------------------------------------------------
// fp64 rescore of flagged points against the fp64 residual. One wave/point.
// ---------------------------------------------------------------------------
__global__ __launch_bounds__(64) void layer_rescore(
    const double* __restrict__ R64,
    const float* __restrict__ cb,
    const double* __restrict__ normD,
    const int* __restrict__ flagList,
    const int* __restrict__ flagCount,
    int* __restrict__ outIdx)
{
    const int cnt = *flagCount;
    const int lane = threadIdx.x;
    for (int i = blockIdx.x; i < cnt; i += gridDim.x) {
        const int n = flagList[i];
        const double* __restrict__ r = R64 + (size_t)n * D_;
        double best = -1.0e300;
        int bi = K_;
        for (int k = lane; k < K_; k += 64) {
            const float* __restrict__ c = cb + (size_t)k * D_;
            double a0 = 0.0, a1 = 0.0;
            #pragma unroll 8
            for (int j = 0; j < D_; j += 2) {
                a0 = fma(r[j],     (double)c[j],     a0);
                a1 = fma(r[j + 1], (double)c[j + 1], a1);
            }
            double s = 2.0 * (a0 + a1) - normD[k];
            if (s > best) { best = s; bi = k; }   // strict > : lowest k in lane wins
        }
        #pragma unroll
        for (int off = 32; off > 0; off >>= 1) {
            double ob = __shfl_down(best, off);
            int    oi = __shfl_down(bi, off);
            if (ob > best || (ob == best && oi < bi)) { best = ob; bi = oi; }
        }
        if (lane == 0) outIdx[n] = bi;
    }
}

// ---------------------------------------------------------------------------
extern "C" void kernel_launch(void* const* d_in, const int* in_sizes, int n_in,
                              void* d_out, int out_size, void* d_ws, size_t ws_size,
                              hipStream_t stream)
{
    const float* emb       = (const float*)d_in[0];   // [B, D, T] fp32
    const float* codebooks = (const float*)d_in[1];   // [Q, K, D] fp32
    int* outIdx = (int*)d_out;                        // [Q, B, T] int32

    char* ws = (char*)d_ws;
    double* R64  = (double*)ws;                        size_t off = (size_t)N_ * D_ * 8;
    double* normD = (double*)(ws + off);               off += (size_t)Q_ * K_ * 8;
    unsigned short* Eh2 = (unsigned short*)(ws + off); off += (size_t)Q_ * K_ * D_ * 2;
    unsigned short* El2 = (unsigned short*)(ws + off); off += (size_t)Q_ * K_ * D_ * 2;
    float* cNorm    = (float*)(ws + off);              off += (size_t)Q_ * K_ * 4;
    int*   flagList = (int*)(ws + off);                off += (size_t)N_ * 4;
    int*   counters = (int*)(ws + off);                off += (size_t)Q_ * 4;

    hipMemsetAsync(counters, 0, Q_ * 4, stream);

    dim3 tb(32, 8, 1);
    dim3 tg((T_ + 31) / 32, D_ / 32, B_);
    transpose_kernel<<<tg, tb, 0, stream>>>(emb, R64);
    split_cb_kernel<<<(Q_ * K_ * D_) / 256, 256, 0, stream>>>(codebooks, Eh2, El2);
    norms_kernel<<<Q_ * K_, 64, 0, stream>>>(codebooks, cNorm, normD);

    for (int q = 0; q < Q_; ++q) {
        int* oq = outIdx + (size_t)q * N_;
        const int* prevIdx = (q > 0) ? (outIdx + (size_t)(q - 1) * N_) : nullptr;
        const float* cbPrev = codebooks + (size_t)(q > 0 ? q - 1 : 0) * K_ * D_;
        layer_fast<<<N_ / 64, 256, 0, stream>>>(
            R64, prevIdx, cbPrev,
            Eh2 + (size_t)q * K_ * D_, El2 + (size_t)q * K_ * D_,
            cNorm + (size_t)q * K_, oq, flagList, counters + q);
        layer_rescore<<<2048, 64, 0, stream>>>(
            R64, codebooks + (size_t)q * K_ * D_, normD + (size_t)q * K_,
            flagList, counters + q, oq);
    }
}

// Round 9
// 5739.815 us; speedup vs baseline: 2.1005x; 1.4041x over previous
//
#include <hip/hip_runtime.h>
#include <hip/hip_bf16.h>

// Problem constants: B=32, D=128, T=2250, Q=32, K=1024
#define B_ 32
#define D_ 128
#define T_ 2250
#define Q_ 32
#define K_ 1024
#define N_ (B_ * T_)      // 72000 = 64 * 1125
#define TAU 0.25f
#define COFF 640.0f       // score offset: v = 2 r.e + (COFF - ||e||^2), positive for this data

typedef _Float16 half8 __attribute__((ext_vector_type(8)));
typedef float f32x4 __attribute__((ext_vector_type(4)));

__device__ __forceinline__ unsigned int pack2h(float a, float b) {
    _Float16 ha = (_Float16)a, hb = (_Float16)b;
    unsigned short ua = *(unsigned short*)&ha, ub = *(unsigned short*)&hb;
    return (unsigned int)ua | ((unsigned int)ub << 16);
}

// ---------------------------------------------------------------------------
// Transpose embeddings [B, D, T] -> R64 [N,128] fp64 (n = b*T + t)
// ---------------------------------------------------------------------------
__global__ void transpose_kernel(const float* __restrict__ emb,
                                 double* __restrict__ R64)
{
    __shared__ float tile[32][33];
    const int b  = blockIdx.z;
    const int t0 = blockIdx.x * 32;
    const int d0 = blockIdx.y * 32;

    for (int i = threadIdx.y; i < 32; i += 8) {
        int t = t0 + threadIdx.x;
        int d = d0 + i;
        tile[i][threadIdx.x] = (t < T_) ? emb[((size_t)b * D_ + d) * T_ + t] : 0.0f;
    }
    __syncthreads();
    for (int i = threadIdx.y; i < 32; i += 8) {
        int t = t0 + i;
        if (t < T_) {
            size_t o = ((size_t)b * T_ + t) * D_ + d0 + threadIdx.x;
            R64[o] = (double)tile[threadIdx.x][i];
        }
    }
}

// ---------------------------------------------------------------------------
// Codebook conversion: E16 = fp16(2*e)   [Q*K*D]
// ---------------------------------------------------------------------------
__global__ void cvt_cb_kernel(const float* __restrict__ cbs,
                              _Float16* __restrict__ E16)
{
    int i = blockIdx.x * 256 + threadIdx.x;   // Q*K*D threads exactly
    E16[i] = (_Float16)(2.0f * cbs[i]);
}

// ---------------------------------------------------------------------------
// Per-code norms: cNorm = COFF - ||e||^2 (fp32), normD = ||e||^2 (fp64)
// ---------------------------------------------------------------------------
__global__ __launch_bounds__(64) void norms_kernel(const float* __restrict__ codebooks,
                                                   float* __restrict__ cNorm,
                                                   double* __restrict__ normD)
{
    const int code = blockIdx.x;            // 0 .. Q*K-1
    const float* e = codebooks + (size_t)code * D_;
    const int lane = threadIdx.x;
    float f0 = e[lane];
    float f1 = e[lane + 64];
    double acc = (double)f0 * (double)f0 + (double)f1 * (double)f1;
    #pragma unroll
    for (int off = 32; off > 0; off >>= 1) acc += __shfl_down(acc, off);
    if (lane == 0) {
        normD[code] = acc;
        cNorm[code] = COFF - (float)acc;
    }
}

// ---------------------------------------------------------------------------
// fp16 single-pass MFMA fast pass with fused fp64 residual update.
// Block = 64 points x ALL 1024 codes; 256 threads = 4 waves.
// Stripe = 128 codes; wave w owns codes [w*32, w*32+32) of each stripe.
// A = fp16(residual), 16 KB LDS, XOR-swizzled. B = fp16(2e) from L2,
// double-buffered across c-groups and stripe boundaries.
// Error model: score err ~<=0.1 worst << TAU; flagged near-ties resolved
// by the fp64 rescore (correctness machinery proven R2-R8).
// ---------------------------------------------------------------------------
__global__ __launch_bounds__(256) void layer_fast(
    double* __restrict__ R64,                 // [N,128] read/modify/write
    const int* __restrict__ prevIdx,          // [N] prev layer's indices (null for q==0)
    const float* __restrict__ cbPrev,         // [K,128] prev layer's fp32 codebook
    const _Float16* __restrict__ E16,         // [K,128] fp16(2e), layer slice
    const float* __restrict__ cNorm,          // [K] COFF - ||e||^2
    int* __restrict__ outIdx,
    int* __restrict__ flagList,
    int* __restrict__ flagCount)
{
    __shared__ __align__(16) char lds[16384];  // A fp16 [64 rows x 256 B]

    const int tid  = threadIdx.x;
    const int lane = tid & 63;
    const int w    = tid >> 6;
    const int mBase = blockIdx.x * 64;        // grid 1125 -> exact, no guards

    // ---- Prologue: fused fp64 residual update + fp16 convert into LDS ----
    {
        double2* R64v = (double2*)R64;
        const float2* cbv = (const float2*)cbPrev;
        const int d = lane * 2;                   // dims d, d+1
        const int gsh = ((d >> 3) << 4);          // granule*16
        const int bofs = (d & 7) * 2;             // byte offset within granule
        #pragma unroll 8
        for (int k = 0; k < 16; ++k) {
            const int row = k * 4 + w;            // wave-uniform local row
            const int grow = mBase + row;
            double2 rv = R64v[(size_t)grow * 64 + lane];
            double rx = rv.x, ry = rv.y;
            if (prevIdx) {
                int code = prevIdx[grow];                    // wave-uniform
                float2 ev = cbv[(size_t)code * 64 + lane];   // coalesced row
                rx -= (double)ev.x;
                ry -= (double)ev.y;
                double2 nv; nv.x = rx; nv.y = ry;
                R64v[(size_t)grow * 64 + lane] = nv;
            }
            const int lofs = row * 256 + (gsh ^ ((row & 15) << 4)) + bofs;
            *(unsigned int*)(lds + lofs) = pack2h((float)rx, (float)ry);
        }
    }
    __syncthreads();

    const int l15  = lane & 15;
    const int quad = lane >> 4;

    // A fragment addressing (XOR-swizzled granules; frag rows have row&15==l15)
    const int aRowByte = l15 * 256;               // + i*4096 for i-th 16-row group
    int gofs[4];
    #pragma unroll
    for (int c = 0; c < 4; ++c) gofs[c] = (((c * 4 + quad) ^ l15) << 4);

    // B global lane base: code row = st*128 + w*32 + j*16 + l15 (256 B rows)
    const size_t bLane = ((size_t)(w * 32 + l15)) * 256 + (size_t)quad * 16;
    const char* BB = (const char*)E16 + bLane;

    // packed running top-2 for this lane's 16 points (s = i*4 + r)
    unsigned int b1[16], b2[16];
    #pragma unroll
    for (int s = 0; s < 16; ++s) { b1[s] = 0u; b2[s] = 0u; }

    // prefetch (st=0, c=0) B fragments
    half8 bc[2];
    #pragma unroll
    for (int j = 0; j < 2; ++j) bc[j] = *(const half8*)(BB + j * 4096);

    #pragma unroll 1
    for (int st = 0; st < 8; ++st) {
        f32x4 acc[4][2];
        #pragma unroll
        for (int i = 0; i < 4; ++i)
            #pragma unroll
            for (int j = 0; j < 2; ++j) acc[i][j] = (f32x4){0.f, 0.f, 0.f, 0.f};

        #pragma unroll
        for (int c = 0; c < 4; ++c) {
            // prefetch next c-group (crossing stripe boundaries)
            half8 bn[2];
            const bool hn = (c < 3) || (st < 7);
            if (hn) {
                size_t noff = (c < 3) ? ((size_t)st * 32768 + (size_t)(c + 1) * 64)
                                      : ((size_t)(st + 1) * 32768);
                #pragma unroll
                for (int j = 0; j < 2; ++j) bn[j] = *(const half8*)(BB + noff + j * 4096);
            }
            half8 ah[4];
            #pragma unroll
            for (int i = 0; i < 4; ++i)
                ah[i] = *(const half8*)(lds + aRowByte + i * 4096 + gofs[c]);
            #pragma unroll
            for (int i = 0; i < 4; ++i)
                #pragma unroll
                for (int j = 0; j < 2; ++j)
                    acc[i][j] = __builtin_amdgcn_mfma_f32_16x16x32_f16(ah[i], bc[j], acc[i][j], 0, 0, 0);
            if (hn) {
                bc[0] = bn[0]; bc[1] = bn[1];
            }
        }

        // epilogue: pack scores, update packed top-2
        #pragma unroll
        for (int j = 0; j < 2; ++j) {
            const int code = st * 128 + w * 32 + j * 16 + l15;
            const float cn = cNorm[code];
            const unsigned int invc = 1023u - (unsigned int)code;
            #pragma unroll
            for (int i = 0; i < 4; ++i)
                #pragma unroll
                for (int r = 0; r < 4; ++r) {
                    float v = fmaxf(acc[i][j][r] + cn, 1.0f);    // positive -> uint-ordered
                    unsigned int p = (__float_as_uint(v) & 0xFFFFFC00u) | invc;
                    const int s = i * 4 + r;
                    unsigned int t  = (b1[s] > p) ? b1[s] : p;
                    unsigned int mn = (b1[s] < p) ? b1[s] : p;
                    b2[s] = (b2[s] > mn) ? b2[s] : mn;
                    b1[s] = t;
                }
        }
    }

    // ---- cross-l15 merge (butterfly over low 4 lane bits), packed ----
    #pragma unroll
    for (int m = 1; m < 16; m <<= 1) {
        #pragma unroll
        for (int s = 0; s < 16; ++s) {
            unsigned int o1 = (unsigned int)__shfl_xor((int)b1[s], m);
            unsigned int o2 = (unsigned int)__shfl_xor((int)b2[s], m);
            unsigned int n1 = (b1[s] > o1) ? b1[s] : o1;
            unsigned int mn = (b1[s] < o1) ? b1[s] : o1;
            unsigned int mx2 = (b2[s] > o2) ? b2[s] : o2;
            b2[s] = (mn > mx2) ? mn : mx2;
            b1[s] = n1;
        }
    }

    // ---- cross-wave merge (4 waves = 4 code bands) via LDS ----
    __syncthreads();                     // done with A region
    unsigned int* m1 = (unsigned int*)lds;            // [4][64]
    unsigned int* m2 = (unsigned int*)(lds + 1024);
    if (l15 == 0) {
        #pragma unroll
        for (int i = 0; i < 4; ++i)
            #pragma unroll
            for (int r = 0; r < 4; ++r) {
                int p = i * 16 + quad * 4 + r;
                m1[w * 64 + p] = b1[i * 4 + r];
                m2[w * 64 + p] = b2[i * 4 + r];
            }
    }
    __syncthreads();
    if (tid < 64) {
        unsigned int f1 = m1[tid], f2 = m2[tid];
        #pragma unroll
        for (int ww = 1; ww < 4; ++ww) {
            unsigned int c1 = m1[ww * 64 + tid], c2 = m2[ww * 64 + tid];
            unsigned int mn  = (f1 < c1) ? f1 : c1;
            f1               = (f1 > c1) ? f1 : c1;
            unsigned int mx2 = (f2 > c2) ? f2 : c2;
            f2 = (mn > mx2) ? mn : mx2;
        }
        const int n = mBase + tid;
        outIdx[n] = 1023 - (int)(f1 & 0x3FFu);
        float g1 = __uint_as_float(f1 & 0xFFFFFC00u);
        float g2 = __uint_as_float(f2 & 0xFFFFFC00u);
        if (g1 - g2 < TAU) {
            int pos = atomicAdd(flagCount, 1);
            flagList[pos] = n;
        }
    }
}

// ---------------------------------------------------------------------------
// fp64 rescore of flagged points against the fp64 residual. One wave/point.
// ---------------------------------------------------------------------------
__global__ __launch_bounds__(64) void layer_rescore(
    const double* __restrict__ R64,
    const float* __restrict__ cb,
    const double* __restrict__ normD,
    const int* __restrict__ flagList,
    const int* __restrict__ flagCount,
    int* __restrict__ outIdx)
{
    const int cnt = *flagCount;
    const int lane = threadIdx.x;
    for (int i = blockIdx.x; i < cnt; i += gridDim.x) {
        const int n = flagList[i];
        const double* __restrict__ r = R64 + (size_t)n * D_;
        double best = -1.0e300;
        int bi = K_;
        for (int k = lane; k < K_; k += 64) {
            const float* __restrict__ c = cb + (size_t)k * D_;
            double a0 = 0.0, a1 = 0.0;
            #pragma unroll 8
            for (int j = 0; j < D_; j += 2) {
                a0 = fma(r[j],     (double)c[j],     a0);
                a1 = fma(r[j + 1], (double)c[j + 1], a1);
            }
            double s = 2.0 * (a0 + a1) - normD[k];
            if (s > best) { best = s; bi = k; }   // strict > : lowest k in lane wins
        }
        #pragma unroll
        for (int off = 32; off > 0; off >>= 1) {
            double ob = __shfl_down(best, off);
            int    oi = __shfl_down(bi, off);
            if (ob > best || (ob == best && oi < bi)) { best = ob; bi = oi; }
        }
        if (lane == 0) outIdx[n] = bi;
    }
}

// ---------------------------------------------------------------------------
extern "C" void kernel_launch(void* const* d_in, const int* in_sizes, int n_in,
                              void* d_out, int out_size, void* d_ws, size_t ws_size,
                              hipStream_t stream)
{
    const float* emb       = (const float*)d_in[0];   // [B, D, T] fp32
    const float* codebooks = (const float*)d_in[1];   // [Q, K, D] fp32
    int* outIdx = (int*)d_out;                        // [Q, B, T] int32

    char* ws = (char*)d_ws;
    double* R64  = (double*)ws;                        size_t off = (size_t)N_ * D_ * 8;
    double* normD = (double*)(ws + off);               off += (size_t)Q_ * K_ * 8;
    _Float16* E16 = (_Float16*)(ws + off);             off += (size_t)Q_ * K_ * D_ * 2;
    float* cNorm    = (float*)(ws + off);              off += (size_t)Q_ * K_ * 4;
    int*   flagList = (int*)(ws + off);                off += (size_t)N_ * 4;
    int*   counters = (int*)(ws + off);                off += (size_t)Q_ * 4;

    hipMemsetAsync(counters, 0, Q_ * 4, stream);

    dim3 tb(32, 8, 1);
    dim3 tg((T_ + 31) / 32, D_ / 32, B_);
    transpose_kernel<<<tg, tb, 0, stream>>>(emb, R64);
    cvt_cb_kernel<<<(Q_ * K_ * D_) / 256, 256, 0, stream>>>(codebooks, E16);
    norms_kernel<<<Q_ * K_, 64, 0, stream>>>(codebooks, cNorm, normD);

    for (int q = 0; q < Q_; ++q) {
        int* oq = outIdx + (size_t)q * N_;
        const int* prevIdx = (q > 0) ? (outIdx + (size_t)(q - 1) * N_) : nullptr;
        const float* cbPrev = codebooks + (size_t)(q > 0 ? q - 1 : 0) * K_ * D_;
        layer_fast<<<N_ / 64, 256, 0, stream>>>(
            R64, prevIdx, cbPrev,
            E16 + (size_t)q * K_ * D_,
            cNorm + (size_t)q * K_, oq, flagList, counters + q);
        layer_rescore<<<2048, 64, 0, stream>>>(
            R64, codebooks + (size_t)q * K_ * D_, normD + (size_t)q * K_,
            flagList, counters + q, oq);
    }
}